// Round 8
// baseline (330.594 us; speedup 1.0000x reference)
//
#include <hip/hip_runtime.h>
#include <stdint.h>

#define S_LEN 2048
#define NH 16
#define DKH 64
#define NB 4
#define DM 1024
#define MROWS (NB * S_LEN)  // 8192

typedef __attribute__((ext_vector_type(4))) float f32x4;
typedef __attribute__((ext_vector_type(8))) short bf16x8;
typedef __attribute__((ext_vector_type(4))) unsigned int u32x4;

static __device__ __forceinline__ unsigned short f2bf(float x) {
    unsigned int u = __builtin_bit_cast(unsigned int, x);
    return (unsigned short)((u + 0x7FFFu + ((u >> 16) & 1u)) >> 16);
}
// packed fp32x2 -> bf16x2 (RNE), single HW instruction (T12)
static __device__ __forceinline__ unsigned int cvtpk(float lo, float hi) {
    unsigned int r;
    asm("v_cvt_pk_bf16_f32 %0, %1, %2" : "=v"(r) : "v"(lo), "v"(hi));
    return r;
}

// CK-style addrspace cast via uintptr_t (apertures are 4GiB-aligned, low 32 bits = LDS offset)
static __device__ __forceinline__ void gld_lds16(const void* g, void* lds) {
    auto gp = (const __attribute__((address_space(1))) unsigned int*)(uintptr_t)(g);
    auto lp = (__attribute__((address_space(3))) unsigned int*)(uintptr_t)(lds);
    __builtin_amdgcn_global_load_lds(gp, lp, 16, 0, 0);
}

// ---------------- fp32 -> bf16 convert for the 4 weight matrices ----------------
__global__ __launch_bounds__(256) void cvt4_f32_bf16(
    const float* __restrict__ i0, const float* __restrict__ i1, const float* __restrict__ i2, const float* __restrict__ i3,
    unsigned short* __restrict__ o0, unsigned short* __restrict__ o1, unsigned short* __restrict__ o2, unsigned short* __restrict__ o3,
    int nvec)
{
    const float* in = (blockIdx.z == 0) ? i0 : (blockIdx.z == 1) ? i1 : (blockIdx.z == 2) ? i2 : i3;
    unsigned short* out = (blockIdx.z == 0) ? o0 : (blockIdx.z == 1) ? o1 : (blockIdx.z == 2) ? o2 : o3;
    const int stride = gridDim.x * blockDim.x;
    for (int i = blockIdx.x * blockDim.x + threadIdx.x; i < nvec; i += stride) {
        float4 v = ((const float4*)in)[i];
        ushort4 r;
        r.x = f2bf(v.x); r.y = f2bf(v.y); r.z = f2bf(v.z); r.w = f2bf(v.w);
        ((ushort4*)out)[i] = r;
    }
}

// ---------------- NT GEMM: C[m,n] = sum_k A[m,k]*B[n,k], M=8192 N=1024 K=1024 ----------------
// 128x128 tile, BK=64, 256 threads (4 waves, 2x2), 16x16x32 bf16 MFMA.
// T1: bijective XCD swizzle so all 8 n-blocks of an A-panel run consecutively on ONE XCD.
// T2: LDS chunk swizzle phys = log ^ (row&7); read koff applies the same XOR.
//   MODE 1: A is FP32 (activations) -- fused convert: reg-stage + v_cvt_pk + swizzled ds_write.
//           B bf16 via gld_lds (pre-swizzled source, linear dest).
//           z=0,1 -> bf16 head-split [B,H,S,64] (z==0 scaled by qscale);
//           z=2   -> bf16 TRANSPOSED per-head V^T [B,H,64,S] (8B-vectorized stores).
//   MODE 2: A,B bf16 via gld_lds; fp32 [M,N] row-major C.
template <int MODE>
__global__ __launch_bounds__(256) void gemm_bt(
    const void* __restrict__ A0, const void* __restrict__ A1, const void* __restrict__ A2,
    const unsigned short* __restrict__ B0, const unsigned short* __restrict__ B1, const unsigned short* __restrict__ B2,
    void* __restrict__ C0, void* __restrict__ C1, void* __restrict__ C2, float qscale)
{
    __shared__ __align__(16) unsigned short As[128 * 64];
    __shared__ __align__(16) unsigned short Bs[128 * 64];

    // T1 bijective XCD swizzle (nwg % 8 == 0 always here)
    const int nwg = gridDim.x * gridDim.y * gridDim.z;
    const int bid = blockIdx.x + gridDim.x * (blockIdx.y + gridDim.y * blockIdx.z);
    const int swz = (bid & 7) * (nwg >> 3) + (bid >> 3);
    const int bx = swz & 7;              // n-block
    const int by = (swz >> 3) & 63;      // m-panel
    const int bz = swz >> 9;             // tensor index (0 for MODE 2)

    const void* Av = (bz == 0) ? A0 : (bz == 1) ? A1 : A2;
    const unsigned short* B = (bz == 0) ? B0 : (bz == 1) ? B1 : B2;
    void* C = (bz == 0) ? C0 : (bz == 1) ? C1 : C2;
    const float cscale = (MODE == 1 && bz == 0) ? qscale : 1.0f;

    const int t = threadIdx.x;
    const int w = t >> 6, l = t & 63;
    const int wr = w >> 1, wc = w & 1;
    const int m0 = by * 128, n0 = bx * 128;

    f32x4 acc[4][4] = {};

    // staging geometry: thread t covers row (t>>3)+32*i, 16B chunk (t&7)
    const int srow = t >> 3, schp = t & 7;
    const int scol = ((schp ^ (srow & 7)) << 3);  // pre-swizzled source col (gld_lds paths)
    const unsigned short* Bg = B + (size_t)(n0 + srow) * 1024 + scol;
    unsigned short* BsW = &Bs[w * 512];
    // MODE 2 A path (bf16, gld_lds)
    const unsigned short* Ag16 = (const unsigned short*)Av + (size_t)(m0 + srow) * 1024 + scol;
    unsigned short* AsW = &As[w * 512];
    // MODE 1 A path (fp32, reg-staged): LINEAR source, swizzled ds_write dest
    const float* Ag32 = (const float*)Av + (size_t)(m0 + srow) * 1024 + schp * 8;
    unsigned short* AsD = &As[srow * 64 + ((schp ^ (srow & 7)) << 3)];

    for (int kt = 0; kt < 16; ++kt) {
        __syncthreads();
        const int kb = kt * 64;
        if constexpr (MODE == 1) {
            float4 v0[4], v1[4];
#pragma unroll
            for (int i = 0; i < 4; ++i) {
                const float* p = Ag32 + (size_t)i * 32 * 1024 + kb;
                v0[i] = *(const float4*)p;
                v1[i] = *(const float4*)(p + 4);
            }
#pragma unroll
            for (int i = 0; i < 4; ++i)
                gld_lds16(Bg + (size_t)i * 32 * 1024 + kb, BsW + i * 2048);
#pragma unroll
            for (int i = 0; i < 4; ++i) {
                u32x4 pk4;
                pk4[0] = cvtpk(v0[i].x, v0[i].y);
                pk4[1] = cvtpk(v0[i].z, v0[i].w);
                pk4[2] = cvtpk(v1[i].x, v1[i].y);
                pk4[3] = cvtpk(v1[i].z, v1[i].w);
                *(u32x4*)(AsD + i * 2048) = pk4;
            }
        } else {
#pragma unroll
            for (int i = 0; i < 4; ++i) {
                gld_lds16(Ag16 + (size_t)i * 32 * 1024 + kb, AsW + i * 2048);
                gld_lds16(Bg + (size_t)i * 32 * 1024 + kb, BsW + i * 2048);
            }
        }
        __syncthreads();
#pragma unroll
        for (int kk = 0; kk < 2; ++kk) {
            // fragment rows have row&7 == l&7 -> phys chunk = (kk*4 + (l>>4)) ^ (l&7)
            const int koff = (((kk * 4 + (l >> 4)) ^ (l & 7)) << 3);
            bf16x8 af[4], bfr[4];
#pragma unroll
            for (int m = 0; m < 4; ++m)
                af[m] = *(const bf16x8*)&As[(wr * 64 + m * 16 + (l & 15)) * 64 + koff];
#pragma unroll
            for (int n = 0; n < 4; ++n)
                bfr[n] = *(const bf16x8*)&Bs[(wc * 64 + n * 16 + (l & 15)) * 64 + koff];
#pragma unroll
            for (int m = 0; m < 4; ++m)
#pragma unroll
                for (int n = 0; n < 4; ++n)
                    acc[m][n] = __builtin_amdgcn_mfma_f32_16x16x32_bf16(af[m], bfr[n], acc[m][n], 0, 0, 0);
        }
    }

#pragma unroll
    for (int m = 0; m < 4; ++m) {
#pragma unroll
        for (int n = 0; n < 4; ++n) {
            const int rowb = m0 + wr * 64 + m * 16 + (l >> 4) * 4;       // +r = b*2048 + s
            const int col  = n0 + wc * 64 + n * 16 + (l & 15);           // = h*64 + dk
            if (MODE == 1 && bz == 2) {
                // V^T store: [bh][dk][s], 4 consecutive s per lane -> 8B store
                const int bh = (rowb >> 11) * 16 + (col >> 6);
                const int dk = col & 63;
                const int s0 = rowb & 2047;
                const unsigned int w0 = cvtpk(acc[m][n][0], acc[m][n][1]);
                const unsigned int w1 = cvtpk(acc[m][n][2], acc[m][n][3]);
                *(uint2*)&((unsigned short*)C)[((size_t)bh * 64 + dk) * 2048 + s0] = make_uint2(w0, w1);
            } else {
#pragma unroll
                for (int r = 0; r < 4; ++r) {
                    const int row = rowb + r;
                    if (MODE == 1) {
                        ((unsigned short*)C)[(size_t)((row >> 11) * 16 + (col >> 6)) * (S_LEN * 64) +
                                             (size_t)(row & 2047) * 64 + (col & 63)] = f2bf(acc[m][n][r] * cscale);
                    } else {
                        ((float*)C)[(size_t)row * 1024 + col] = acc[m][n][r];
                    }
                }
            }
        }
    }
}

// ---------------- causal flash attention (swapped-QK^T, in-register softmax) ----------------
// Q/K [B*H, S, 64] bf16 (Q pre-scaled by 1/8), V^T [B*H, 64, S] bf16 -> Ao [B, S, 1024] bf16
// 512 threads = 8 waves, each wave owns 16 q-rows; KVBLK = 64.
// K and V^T double-buffered in LDS (4 x 8 KiB), staged via global_load_lds with pre-swizzled
// source (ch_phys = ch_log ^ (row&7)); ONE __syncthreads per tile, stage(kv+1) issued right
// after it (T3 minimum 2-phase: latency hides under compute of tile kv).
// After mfma(A=K, B=Q): sc[nb] = S^T[k = kv0+nb*16+4g+r][q = c], g=l>>4, c=l&15.
__global__ __launch_bounds__(512, 4) void attn_fwd(
    const unsigned short* __restrict__ Qh, const unsigned short* __restrict__ Kh,
    const unsigned short* __restrict__ Vth, unsigned short* __restrict__ Ao)
{
    __shared__ __align__(16) unsigned short Kts[2 * 4096];  // [buf][row 0..63][chunk 0..7][8]
    __shared__ __align__(16) unsigned short Vts[2 * 4096];  // [buf][dk 0..63][chunk 0..7][8]

    const int t = threadIdx.x, w = t >> 6, l = t & 63;
    const int g = l >> 4, c = l & 15;
    const int bid = blockIdx.x;
    const int qi = 15 - (bid >> 6);   // heavy-first: 32-tile blocks dispatch first
    const int bh = bid & 63;          // same-bh blocks land on same XCD (64 % 8 == 0)
    const int b = bh >> 4, h = bh & 15;
    const int q0 = qi * 128;

    const unsigned short* Qg  = Qh  + (size_t)bh * (S_LEN * 64);
    const unsigned short* Kg  = Kh  + (size_t)bh * (S_LEN * 64);
    const unsigned short* Vtg = Vth + (size_t)bh * (64 * S_LEN);

    // Q B-frags for this wave's 16 rows (held in regs for all tiles)
    const int qrow = q0 + w * 16 + c;
    const unsigned short* Qp = Qg + (size_t)qrow * 64 + g * 8;
    bf16x8 qf[2];
    qf[0] = *(const bf16x8*)(Qp);
    qf[1] = *(const bf16x8*)(Qp + 32);

    // staging: thread t handles 16B-unit L=t of each tile (512 units = 8KB).
    // K: row = t>>3 (64 rows x 64 dk), phys chunk = t&7, logical chunk = phys ^ (row&7)
    const int krow = t >> 3, kchp = t & 7;
    const unsigned short* Ksrc = Kg + (size_t)krow * 64 + ((kchp ^ (krow & 7)) << 3);
    // V: dk = t>>3 (64 dk x 64 kv), src row stride 2048
    const unsigned short* Vsrc = Vtg + (size_t)(t >> 3) * 2048 + ((kchp ^ ((t >> 3) & 7)) << 3);
    const int ldsW = w * 512;  // wave-uniform dest base (lane adds l*16B)

    float m_run = -1e30f, l_run = 0.0f;
    f32x4 oacc[4] = {};

    const int ntile = 2 * qi + 2;
    // prologue: stage tile 0 into buf 0
    gld_lds16(Ksrc, &Kts[ldsW]);
    gld_lds16(Vsrc, &Vts[ldsW]);

    for (int kv = 0; kv < ntile; ++kv) {
        const int kv0 = kv * 64;
        __syncthreads();  // stage(kv) drained & visible; all reads of buf[(kv+1)&1] done

        if (kv + 1 < ntile) {  // stage next tile (latency hides under this tile's compute)
            const int nb4 = ((kv + 1) & 1) * 4096;
            gld_lds16(Ksrc + (size_t)(kv0 + 64) * 64, &Kts[nb4 + ldsW]);
            gld_lds16(Vsrc + (kv0 + 64), &Vts[nb4 + ldsW]);
        }

        // skip fully-masked tiles for this wave (wave-uniform; barriers stay outside)
        if (kv0 > q0 + w * 16 + 15) continue;

        const unsigned short* Kb = &Kts[(kv & 1) * 4096];
        const unsigned short* Vb = &Vts[(kv & 1) * 4096];

        // --- QK^T (swapped): sc[nb] = S^T[k][q] ---
        f32x4 sc[4] = {};
#pragma unroll
        for (int kk = 0; kk < 2; ++kk) {
#pragma unroll
            for (int nb = 0; nb < 4; ++nb) {
                const int row = nb * 16 + c;
                const int chp = (kk * 4 + g) ^ (c & 7);
                const bf16x8 kfr = *(const bf16x8*)&Kb[row * 64 + chp * 8];
                sc[nb] = __builtin_amdgcn_mfma_f32_16x16x32_bf16(kfr, qf[kk], sc[nb], 0, 0, 0);
            }
        }

        // --- causal mask (only the last two tiles can touch the diagonal) ---
        if (kv >= ntile - 2) {
#pragma unroll
            for (int nb = 0; nb < 4; ++nb)
#pragma unroll
                for (int r = 0; r < 4; ++r)
                    if (kv0 + nb * 16 + 4 * g + r > qrow) sc[nb][r] = -1e30f;
        }

        // --- online softmax, in-register (q = c per lane), defer-max (T13, THR=8) ---
        float mx = -1e30f;
#pragma unroll
        for (int nb = 0; nb < 4; ++nb)
#pragma unroll
            for (int r = 0; r < 4; ++r) mx = fmaxf(mx, sc[nb][r]);
        mx = fmaxf(mx, __shfl_xor(mx, 16));
        mx = fmaxf(mx, __shfl_xor(mx, 32));

        if (!__all(mx - m_run <= 8.0f)) {
            const float mnew = fmaxf(m_run, mx);
            const float alpha = __expf(m_run - mnew);
            m_run = mnew;
            float af[4];
#pragma unroll
            for (int r = 0; r < 4; ++r) af[r] = __shfl(alpha, 4 * g + r);
#pragma unroll
            for (int db = 0; db < 4; ++db)
#pragma unroll
                for (int r = 0; r < 4; ++r) oacc[db][r] *= af[r];
            l_run *= alpha;
        }

        float s = 0.0f;
#pragma unroll
        for (int nb = 0; nb < 4; ++nb)
#pragma unroll
            for (int r = 0; r < 4; ++r) {
                const float p = __expf(sc[nb][r] - m_run);
                sc[nb][r] = p;
                s += p;
            }
        s += __shfl_xor(s, 16);
        s += __shfl_xor(s, 32);
        l_run += s;

        // --- pack P to bf16 pairs (v_cvt_pk, T12); redistribute into PV A-frags via shfl ---
        unsigned int pk[4][2];
#pragma unroll
        for (int nb = 0; nb < 4; ++nb) {
            pk[nb][0] = cvtpk(sc[nb][0], sc[nb][1]);
            pk[nb][1] = cvtpk(sc[nb][2], sc[nb][3]);
        }
        const int srcA = 32 * (g & 1) + c;
        const int srcB = srcA + 16;
        const bool hi = (g >= 2);   // selects k-block nb = 2*kk2 + 1
        unsigned int apw[2][4];
#pragma unroll
        for (int kk2 = 0; kk2 < 2; ++kk2) {
            const unsigned int a0 = __shfl(pk[2 * kk2][0], srcA), b0 = __shfl(pk[2 * kk2 + 1][0], srcA);
            const unsigned int a1 = __shfl(pk[2 * kk2][1], srcA), b1 = __shfl(pk[2 * kk2 + 1][1], srcA);
            const unsigned int a2 = __shfl(pk[2 * kk2][0], srcB), b2 = __shfl(pk[2 * kk2 + 1][0], srcB);
            const unsigned int a3 = __shfl(pk[2 * kk2][1], srcB), b3 = __shfl(pk[2 * kk2 + 1][1], srcB);
            apw[kk2][0] = hi ? b0 : a0;
            apw[kk2][1] = hi ? b1 : a1;
            apw[kk2][2] = hi ? b2 : a2;
            apw[kk2][3] = hi ? b3 : a3;
        }

        // --- PV: O += P * V  (A = apw regs, B = V^T rows from LDS, swizzled chunks) ---
#pragma unroll
        for (int kk2 = 0; kk2 < 2; ++kk2) {
            const bf16x8 ap = __builtin_bit_cast(bf16x8, *(const u32x4*)apw[kk2]);
#pragma unroll
            for (int db = 0; db < 4; ++db) {
                const int d = db * 16 + c;
                const int chp = (kk2 * 4 + g) ^ (d & 7);
                const bf16x8 bv = *(const bf16x8*)&Vb[d * 64 + chp * 8];
                oacc[db] = __builtin_amdgcn_mfma_f32_16x16x32_bf16(ap, bv, oacc[db], 0, 0, 0);
            }
        }
    }

    // --- epilogue: normalize, write [B, S, H*64] ---
    float li[4];
#pragma unroll
    for (int r = 0; r < 4; ++r) li[r] = __shfl(l_run, 4 * g + r);
#pragma unroll
    for (int db = 0; db < 4; ++db)
#pragma unroll
        for (int r = 0; r < 4; ++r) {
            const int sq = q0 + w * 16 + 4 * g + r;
            const int col = h * 64 + db * 16 + c;
            Ao[(size_t)b * (S_LEN * 1024) + (size_t)sq * 1024 + col] = f2bf(oacc[db][r] / li[r]);
        }
}

extern "C" void kernel_launch(void* const* d_in, const int* in_sizes, int n_in,
                              void* d_out, int out_size, void* d_ws, size_t ws_size,
                              hipStream_t stream) {
    (void)in_sizes; (void)n_in; (void)out_size; (void)ws_size;
    const float* q_in = (const float*)d_in[0];
    const float* k_in = (const float*)d_in[1];
    const float* v_in = (const float*)d_in[2];
    // d_in[3] = causal mask (tril) -> implemented analytically in attn_fwd
    const float* w_q = (const float*)d_in[4];
    const float* w_k = (const float*)d_in[5];
    const float* w_v = (const float*)d_in[6];
    const float* w_o = (const float*)d_in[7];

    const size_t NELEM = (size_t)MROWS * 1024;  // 8388608
    unsigned short* wqb = (unsigned short*)d_ws;
    unsigned short* wkb = wqb + 1024 * 1024;
    unsigned short* wvb = wkb + 1024 * 1024;
    unsigned short* wob = wvb + 1024 * 1024;
    unsigned short* Qhp = wob + 1024 * 1024;
    unsigned short* Khp = Qhp + NELEM;
    unsigned short* Vtp = Khp + NELEM;   // V^T [B*H, 64, S]
    unsigned short* Aop = Vtp + NELEM;

    cvt4_f32_bf16<<<dim3(256, 1, 4), 256, 0, stream>>>(w_q, w_k, w_v, w_o, wqb, wkb, wvb, wob, 1024 * 1024 / 4);

    gemm_bt<1><<<dim3(8, 64, 3), 256, 0, stream>>>(q_in, k_in, v_in, wqb, wkb, wvb, Qhp, Khp, Vtp, 0.125f);
    attn_fwd<<<dim3(1024), 512, 0, stream>>>(Qhp, Khp, Vtp, Aop);
    gemm_bt<2><<<dim3(8, 64, 1), 256, 0, stream>>>(Aop, nullptr, nullptr, wob, nullptr, nullptr,
                                                   d_out, nullptr, nullptr, 1.0f);
}